// Round 2
// baseline (173.835 us; speedup 1.0000x reference)
//
#include <hip/hip_runtime.h>

// B*H*W = 65536 vectors, dim 64, 512 codes
#define NVEC 65536
#define DIM 64
#define KCODES 512
#define NBLK 1024  // NVEC / 64

// Block: 512 threads = 8 waves. Each wave handles the SAME 64 vectors
// (one per lane) and a wave-uniform slice of 64 codes -> emb reads are
// scalar s_load broadcasts (zero VALU issue cost). Merge 8 partials in LDS.
// Grid: 1024 blocks = 4 blocks/CU = 8 waves/SIMD (full occupancy at 64 VGPR).
__global__ __launch_bounds__(512, 8) void vq_kernel(const float* __restrict__ x,
                                                    const float* __restrict__ emb,
                                                    float* __restrict__ out,
                                                    float* __restrict__ ws) {
    __shared__ float en[KCODES];     // ||e_k||^2
    __shared__ float sdist[8][64];
    __shared__ int   sidx[8][64];
    __shared__ float swl[8];

    const int tid = threadIdx.x;

    // --- codebook norms: one code per thread, coalesced over k ---
    {
        const int k = tid;  // 512 threads == 512 codes
        float s = 0.f;
#pragma unroll
        for (int d = 0; d < DIM; ++d) {
            float v = emb[d * KCODES + k];
            s = fmaf(v, v, s);
        }
        en[k] = s;
    }
    __syncthreads();

    const int wid  = __builtin_amdgcn_readfirstlane(tid >> 6);  // wave id 0..7 (SGPR)
    const int lane = tid & 63;
    const int vec  = blockIdx.x * 64 + lane;
    const float* xv = x + (size_t)vec * DIM;

    // --- ||z||^2 (also warms L1 for the chunked reloads below) ---
    float znorm = 0.f;
#pragma unroll
    for (int d = 0; d < DIM; d += 4) {
        float4 v = *reinterpret_cast<const float4*>(xv + d);
        znorm = fmaf(v.x, v.x, znorm);
        znorm = fmaf(v.y, v.y, znorm);
        znorm = fmaf(v.z, v.z, znorm);
        znorm = fmaf(v.w, v.w, znorm);
    }

    // --- scan this wave's 64-code slice, 8 codes per tile ---
    float best  = 3.4e38f;
    int   bestk = 0;
    const int kbase0 = wid * 64;  // wave-uniform
#pragma unroll 1
    for (int kt = 0; kt < 8; ++kt) {
        const int kb = kbase0 + kt * 8;
        float acc[8] = {0.f, 0.f, 0.f, 0.f, 0.f, 0.f, 0.f, 0.f};
        // d in two chunks of 32 so z stays at 32 VGPRs (8 waves/SIMD needs <=64)
#pragma unroll 1
        for (int dc = 0; dc < 2; ++dc) {
            float zc[32];
#pragma unroll
            for (int i = 0; i < 8; ++i) {
                float4 v = *reinterpret_cast<const float4*>(xv + dc * 32 + i * 4);
                zc[i * 4 + 0] = v.x; zc[i * 4 + 1] = v.y;
                zc[i * 4 + 2] = v.z; zc[i * 4 + 3] = v.w;
            }
#pragma unroll
            for (int d = 0; d < 32; ++d) {
                const float* ep = emb + (dc * 32 + d) * KCODES + kb;  // uniform -> s_load
#pragma unroll
                for (int j = 0; j < 8; ++j) acc[j] = fmaf(zc[d], ep[j], acc[j]);
            }
        }
#pragma unroll
        for (int j = 0; j < 8; ++j) {
            // reference association: (||z||^2 + ||e||^2) - 2*dot, single rounding on fma
            float t    = znorm + en[kb + j];
            float dist = fmaf(-2.0f, acc[j], t);
            if (dist < best) { best = dist; bestk = kb + j; }  // ascending k, first min wins
        }
    }

    sdist[wid][lane] = best;
    sidx[wid][lane]  = bestk;
    __syncthreads();

    // --- epilogue: thread t -> vector v8 = t>>3, dim-octet j8 = t&7 ---
    const int v8 = tid >> 3;
    const int j8 = tid & 7;
    float bd = sdist[0][v8];
    int   bk = sidx[0][v8];
#pragma unroll
    for (int s = 1; s < 8; ++s) {   // slices in ascending-k order; strict < keeps lowest k
        float d2 = sdist[s][v8];
        int   k2 = sidx[s][v8];
        if (d2 < bd) { bd = d2; bk = k2; }
    }

    const int gvec = blockIdx.x * 64 + v8;
    const float* xg = x + (size_t)gvec * DIM + j8 * 8;
    float*       og = out + (size_t)gvec * DIM + j8 * 8;

    float q[8];
#pragma unroll
    for (int i = 0; i < 8; ++i) q[i] = emb[(j8 * 8 + i) * KCODES + bk];
    float4 q0 = make_float4(q[0], q[1], q[2], q[3]);
    float4 q1 = make_float4(q[4], q[5], q[6], q[7]);
    *reinterpret_cast<float4*>(og)     = q0;   // wave covers 8 vecs x 64 dims contiguous
    *reinterpret_cast<float4*>(og + 4) = q1;

    float4 xa = *reinterpret_cast<const float4*>(xg);
    float4 xb = *reinterpret_cast<const float4*>(xg + 4);
    float lossLocal = 0.f;
    {
        float a;
        a = q[0] - xa.x; lossLocal = fmaf(a, a, lossLocal);
        a = q[1] - xa.y; lossLocal = fmaf(a, a, lossLocal);
        a = q[2] - xa.z; lossLocal = fmaf(a, a, lossLocal);
        a = q[3] - xa.w; lossLocal = fmaf(a, a, lossLocal);
        a = q[4] - xb.x; lossLocal = fmaf(a, a, lossLocal);
        a = q[5] - xb.y; lossLocal = fmaf(a, a, lossLocal);
        a = q[6] - xb.z; lossLocal = fmaf(a, a, lossLocal);
        a = q[7] - xb.w; lossLocal = fmaf(a, a, lossLocal);
    }

    // --- block-reduce loss, atomic accumulate, last block finalizes ---
#pragma unroll
    for (int off = 32; off; off >>= 1) lossLocal += __shfl_down(lossLocal, off, 64);
    if (lane == 0) swl[wid] = lossLocal;
    __syncthreads();
    if (tid == 0) {
        float s = 0.f;
#pragma unroll
        for (int i = 0; i < 8; ++i) s += swl[i];
        atomicAdd(&ws[0], s);
        __threadfence();
        unsigned int* cnt = reinterpret_cast<unsigned int*>(ws + 1);
        unsigned int prev = atomicAdd(cnt, 1u);
        if (prev == (unsigned int)(NBLK - 1)) {
            float total = atomicAdd(&ws[0], 0.0f);  // coherent read of final sum
            out[(size_t)NVEC * DIM] = 2.0f * total / (float)((size_t)NVEC * DIM);
        }
    }
}

extern "C" void kernel_launch(void* const* d_in, const int* in_sizes, int n_in,
                              void* d_out, int out_size, void* d_ws, size_t ws_size,
                              hipStream_t stream) {
    const float* x   = (const float*)d_in[0];
    const float* emb = (const float*)d_in[1];
    float* out = (float*)d_out;
    float* ws  = (float*)d_ws;

    hipMemsetAsync(d_ws, 0, 8, stream);  // loss accumulator + block counter
    vq_kernel<<<dim3(NBLK), dim3(512), 0, stream>>>(x, emb, out, ws);
}

// Round 3
// 127.843 us; speedup vs baseline: 1.3597x; 1.3597x over previous
//
#include <hip/hip_runtime.h>

// B*H*W = 65536 vectors, dim 64, 512 codes
#define NVEC 65536
#define DIM 64
#define KCODES 512
#define NBLK 1024  // NVEC / 64

// Block: 256 threads = 4 waves, all covering the SAME 64 vectors (one per
// lane). Each wave scans a wave-uniform slice of 128 codes -> emb reads are
// scalar s_load_dwordx8 broadcasts (zero VALU cost). z[64] stays fully
// register-resident (128-VGPR budget). Merge 4 partials via LDS.
// Grid: 1024 blocks = 4 blocks/CU = 4 waves/SIMD.
__global__ __launch_bounds__(256, 4) void vq_kernel(const float* __restrict__ x,
                                                    const float* __restrict__ emb,
                                                    float* __restrict__ out,
                                                    float* __restrict__ ws) {
    __shared__ float en[KCODES];     // ||e_k||^2
    __shared__ float sdist[4][64];
    __shared__ int   sidx[4][64];
    __shared__ float swl[4];

    const int tid = threadIdx.x;

    // --- codebook norms: coalesced over k ---
    for (int kk = tid; kk < KCODES; kk += 256) {
        float s = 0.f;
#pragma unroll
        for (int d = 0; d < DIM; ++d) {
            float v = emb[d * KCODES + kk];
            s = fmaf(v, v, s);
        }
        en[kk] = s;
    }
    __syncthreads();

    const int wid  = __builtin_amdgcn_readfirstlane(tid >> 6);  // 0..3, SGPR
    const int lane = tid & 63;
    const int vec  = blockIdx.x * 64 + lane;
    const float* xv = x + (size_t)vec * DIM;

    // --- z fully in registers + ||z||^2 ---
    float z[DIM];
#pragma unroll
    for (int d = 0; d < DIM; d += 4) {
        float4 v = *reinterpret_cast<const float4*>(xv + d);
        z[d] = v.x; z[d + 1] = v.y; z[d + 2] = v.z; z[d + 3] = v.w;
    }
    float znorm = 0.f;
#pragma unroll
    for (int d = 0; d < DIM; ++d) znorm = fmaf(z[d], z[d], znorm);

    // --- scan this wave's 128-code slice, 8 codes per tile ---
    float best  = 3.4e38f;
    int   bestk = 0;
    const int kbase0 = wid * 128;  // wave-uniform
#pragma unroll 1
    for (int kt = 0; kt < 16; ++kt) {
        const int kb = kbase0 + kt * 8;
        float acc[8] = {0.f, 0.f, 0.f, 0.f, 0.f, 0.f, 0.f, 0.f};
#pragma unroll
        for (int d = 0; d < DIM; ++d) {
            const float* ep = emb + d * KCODES + kb;  // wave-uniform -> s_load_dwordx8
#pragma unroll
            for (int j = 0; j < 8; ++j) acc[j] = fmaf(z[d], ep[j], acc[j]);
        }
#pragma unroll
        for (int j = 0; j < 8; ++j) {
            // reference association: (||z||^2 + ||e||^2) - 2*dot
            float t    = znorm + en[kb + j];
            float dist = fmaf(-2.0f, acc[j], t);
            if (dist < best) { best = dist; bestk = kb + j; }  // ascending k, first min wins
        }
    }

    sdist[wid][lane] = best;
    sidx[wid][lane]  = bestk;
    __syncthreads();

    // --- epilogue: thread t -> vector v16 = t>>2, dim-block j16 = (t&3)*16 ---
    const int v16 = tid >> 2;
    const int j16 = (tid & 3) * 16;
    float bd = sdist[0][v16];
    int   bk = sidx[0][v16];
#pragma unroll
    for (int s = 1; s < 4; ++s) {   // ascending-k slices; strict < keeps lowest k
        float d2 = sdist[s][v16];
        int   k2 = sidx[s][v16];
        if (d2 < bd) { bd = d2; bk = k2; }
    }

    const int gvec = blockIdx.x * 64 + v16;
    const float* xg = x + (size_t)gvec * DIM + j16;
    float*       og = out + (size_t)gvec * DIM + j16;

    float lossLocal = 0.f;
#pragma unroll
    for (int c = 0; c < 4; ++c) {
        float4 q;
        q.x = emb[(j16 + c * 4 + 0) * KCODES + bk];
        q.y = emb[(j16 + c * 4 + 1) * KCODES + bk];
        q.z = emb[(j16 + c * 4 + 2) * KCODES + bk];
        q.w = emb[(j16 + c * 4 + 3) * KCODES + bk];
        *reinterpret_cast<float4*>(og + c * 4) = q;  // contiguous 4 KB per wave
        float4 xa = *reinterpret_cast<const float4*>(xg + c * 4);
        float a;
        a = q.x - xa.x; lossLocal = fmaf(a, a, lossLocal);
        a = q.y - xa.y; lossLocal = fmaf(a, a, lossLocal);
        a = q.z - xa.z; lossLocal = fmaf(a, a, lossLocal);
        a = q.w - xa.w; lossLocal = fmaf(a, a, lossLocal);
    }

    // --- block-reduce loss, atomic accumulate, last block finalizes ---
#pragma unroll
    for (int off = 32; off; off >>= 1) lossLocal += __shfl_down(lossLocal, off, 64);
    if (lane == 0) swl[wid] = lossLocal;
    __syncthreads();
    if (tid == 0) {
        float s = swl[0] + swl[1] + swl[2] + swl[3];
        atomicAdd(&ws[0], s);
        __threadfence();
        unsigned int* cnt = reinterpret_cast<unsigned int*>(ws + 1);
        unsigned int prev = atomicAdd(cnt, 1u);
        if (prev == (unsigned int)(NBLK - 1)) {
            float total = atomicAdd(&ws[0], 0.0f);  // coherent read of final sum
            out[(size_t)NVEC * DIM] = 2.0f * total / (float)((size_t)NVEC * DIM);
        }
    }
}

extern "C" void kernel_launch(void* const* d_in, const int* in_sizes, int n_in,
                              void* d_out, int out_size, void* d_ws, size_t ws_size,
                              hipStream_t stream) {
    const float* x   = (const float*)d_in[0];
    const float* emb = (const float*)d_in[1];
    float* out = (float*)d_out;
    float* ws  = (float*)d_ws;

    hipMemsetAsync(d_ws, 0, 8, stream);  // loss accumulator + block counter
    vq_kernel<<<dim3(NBLK), dim3(256), 0, stream>>>(x, emb, out, ws);
}